// Round 10
// baseline (907.700 us; speedup 1.0000x reference)
//
#include <hip/hip_runtime.h>
#include <hip/hip_bf16.h>
#include <math.h>

#define N_NODES 100000
#define N_EDGES 1600000
#define F_INN   32
#define F_EE    8
#define HD      64
#define E_SL    (N_EDGES + N_NODES)   // edges + self loops
#define NEG_SLOPE 0.2f
#define MEAN_BLOCKS 256
#define SCAN_BLOCK 512
#define N_SCAN_BLOCKS ((N_NODES + SCAN_BLOCK - 1) / SCAN_BLOCK)   // 196
#define SHARD_W (N_NODES / 8)         // 12500 nodes per XCD shard
#define PERM_BLOCKS 2048              // 256 blocks per shard
#define NPB 32                        // nodes per block in dense kernels (N%32==0 -> 3125 blocks)

// ---------- helpers ----------
__device__ __forceinline__ float waveReduceSum(float v) {
#pragma unroll
    for (int off = 32; off > 0; off >>= 1) v += __shfl_down(v, off, 64);
    return v;
}
__device__ __forceinline__ float bf_lo(uint u) { return __uint_as_float(u << 16); }
__device__ __forceinline__ float bf_hi(uint u) { return __uint_as_float(u & 0xffff0000u); }
__device__ __forceinline__ uint pack_bf2(float a, float b) {
    __hip_bfloat16 ha = __float2bfloat16(a), hb = __float2bfloat16(b);
    unsigned short ua, ub;
    __builtin_memcpy(&ua, &ha, 2); __builtin_memcpy(&ub, &hb, 2);
    return (uint)ua | ((uint)ub << 16);
}

// ---------- K1: we_vec[l][k] = dot(edge_w[l][k,:], att_edge[l,:]) ----------
__global__ void k_init_small(const float* __restrict__ edge_w, const float* __restrict__ att_edge,
                             float* __restrict__ we_vec) {
    int t = threadIdx.x;
    if (t < 16) {
        int l = t >> 3, k = t & 7;
        const float* We = edge_w + l * F_EE * HD + k * HD;
        const float* ae = att_edge + l * HD;
        float s = 0.0f;
#pragma unroll
        for (int j = 0; j < HD; ++j) s += We[j] * ae[j];
        we_vec[l * 8 + k] = s;
    }
}

// ---------- K1b: fold encoder into layer-0 projection: Wc = enc_w@W0, bc = enc_b@W0 ----------
__global__ __launch_bounds__(256) void k_fuse_w(const float* __restrict__ enc_w,
                                                const float* __restrict__ enc_b,
                                                const float* __restrict__ W0,
                                                float* __restrict__ Wc, float* __restrict__ bc) {
    int t = threadIdx.x;
    for (int idx = t; idx < F_INN * HD; idx += 256) {
        int r = idx >> 6, c = idx & 63;
        float s = 0.0f;
#pragma unroll
        for (int k = 0; k < HD; ++k) s += enc_w[r * HD + k] * W0[k * HD + c];
        Wc[idx] = s;
    }
    if (t < HD) {
        float s = 0.0f;
#pragma unroll
        for (int k = 0; k < HD; ++k) s += enc_b[k] * W0[k * HD + t];
        bc[t] = s;
    }
}

// ---------- K2a: fused — mean partials AND edge-ordered records {src, packed bf16 ed01} ----------
__global__ __launch_bounds__(256) void k_mean_edterm(const float* __restrict__ eattr,
                                                     const int* __restrict__ src,
                                                     const float* __restrict__ we_vec,
                                                     float* __restrict__ partials,
                                                     int2* __restrict__ rec_agg) {
    __shared__ float sw[16];
    int t = threadIdx.x;
    if (t < 16) sw[t] = we_vec[t];
    __syncthreads();
    float p[8];
#pragma unroll
    for (int k = 0; k < 8; ++k) p[k] = 0.0f;
    for (int e = blockIdx.x * blockDim.x + t; e < N_EDGES; e += gridDim.x * blockDim.x) {
        const float4* row = (const float4*)(eattr + (size_t)e * F_EE);
        float4 r0 = row[0], r1 = row[1];
        p[0] += r0.x; p[1] += r0.y; p[2] += r0.z; p[3] += r0.w;
        p[4] += r1.x; p[5] += r1.y; p[6] += r1.z; p[7] += r1.w;
        float ed0 = r0.x * sw[0] + r0.y * sw[1] + r0.z * sw[2] + r0.w * sw[3]
                  + r1.x * sw[4] + r1.y * sw[5] + r1.z * sw[6] + r1.w * sw[7];
        float ed1 = r0.x * sw[8] + r0.y * sw[9] + r0.z * sw[10] + r0.w * sw[11]
                  + r1.x * sw[12] + r1.y * sw[13] + r1.z * sw[14] + r1.w * sw[15];
        rec_agg[e] = make_int2(src[e], (int)pack_bf2(ed0, ed1));
    }
#pragma unroll
    for (int k = 0; k < 8; ++k) p[k] = waveReduceSum(p[k]);
    int wave = t >> 6;
    if ((t & 63) == 0) {
        float* dstp = partials + ((size_t)blockIdx.x * 4 + wave) * 8;
#pragma unroll
        for (int k = 0; k < 8; ++k) dstp[k] = p[k];
    }
}

// ---------- K2b: finish mean; ltp = packed bf16 {loop_term0, loop_term1} ----------
__global__ __launch_bounds__(256) void k_mean_final(const float* __restrict__ partials,
                                                    const float* __restrict__ we_vec,
                                                    uint* __restrict__ ltp) {
    __shared__ float red[256];
    __shared__ float mean8[8];
    __shared__ float lt[2];
    int t = threadIdx.x;
    int k = t & 7;
    int chunk = t >> 3;
    float s = 0.0f;
    for (int i = chunk; i < MEAN_BLOCKS * 4; i += 32) s += partials[(size_t)i * 8 + k];
    red[t] = s;
    __syncthreads();
    if (t < 8) {
        float acc = 0.0f;
#pragma unroll
        for (int c = 0; c < 32; ++c) acc += red[c * 8 + t];
        mean8[t] = acc * (1.0f / N_EDGES);
    }
    __syncthreads();
    if (t < 2) {
        float acc = 0.0f;
#pragma unroll
        for (int kk = 0; kk < 8; ++kk) acc += mean8[kk] * we_vec[t * 8 + kk];
        lt[t] = acc;
    }
    __syncthreads();
    if (t == 0) ltp[0] = pack_bf2(lt[0], lt[1]);
}

// ---------- CSR build ----------
__global__ void k_deg_init(int* __restrict__ deg) {
    int i = blockIdx.x * 256 + threadIdx.x;
    if (i < N_NODES) deg[i] = 1;   // self-loop
}

__global__ void k_hist(const int* __restrict__ dst, int* __restrict__ deg) {
    int e = blockIdx.x * 256 + threadIdx.x;   // grid exact: E/256
    atomicAdd(&deg[dst[e]], 1);
}

__global__ __launch_bounds__(SCAN_BLOCK) void k_scan1(const int* __restrict__ deg,
                                                      int* __restrict__ row_ptr,
                                                      int* __restrict__ blk_sums) {
    __shared__ int sd[SCAN_BLOCK];
    int t = threadIdx.x;
    int i = blockIdx.x * SCAN_BLOCK + t;
    int v = (i < N_NODES) ? deg[i] : 0;
    sd[t] = v;
    for (int off = 1; off < SCAN_BLOCK; off <<= 1) {
        __syncthreads();
        int x = (t >= off) ? sd[t - off] : 0;
        __syncthreads();
        sd[t] += x;
    }
    __syncthreads();
    if (i < N_NODES) row_ptr[i] = sd[t] - v;
    if (t == SCAN_BLOCK - 1) blk_sums[blockIdx.x] = sd[t];
}

__global__ __launch_bounds__(256) void k_scan2(int* __restrict__ blk_sums,
                                               int* __restrict__ blk_off) {
    __shared__ int sd[256];
    int t = threadIdx.x;
    int v = (t < N_SCAN_BLOCKS) ? blk_sums[t] : 0;
    sd[t] = v;
    for (int off = 1; off < 256; off <<= 1) {
        __syncthreads();
        int x = (t >= off) ? sd[t - off] : 0;
        __syncthreads();
        sd[t] += x;
    }
    __syncthreads();
    if (t < N_SCAN_BLOCKS) blk_off[t] = sd[t] - v;
}

// finalize row_ptr, init cursor, and drop self-loop marker into the LAST slot of each segment
__global__ void k_scan3(int* __restrict__ row_ptr, const int* __restrict__ blk_off,
                        const int* __restrict__ deg,
                        int* __restrict__ cursor, int* __restrict__ perm) {
    int i = blockIdx.x * 256 + threadIdx.x;
    if (i < N_NODES) {
        int r = row_ptr[i] + blk_off[i / SCAN_BLOCK];
        row_ptr[i] = r;
        cursor[i] = r;
        perm[r + deg[i] - 1] = N_EDGES + i;   // self-loop marker (kB fills [r, r+deg-1))
    }
    if (i == 0) row_ptr[N_NODES] = E_SL;
}

// kB: XCD-sharded perm scatter — shard s = blockIdx&7 handles dst in [s*SHARD_W,(s+1)*SHARD_W)
__global__ __launch_bounds__(256) void k_perm_scatter(const int* __restrict__ dst,
                                                      int* __restrict__ cursor,
                                                      int* __restrict__ perm) {
    int shard = blockIdx.x & 7;
    int lo = shard * SHARD_W, hi = lo + SHARD_W;
    int stride = (PERM_BLOCKS >> 3) * 256;
    for (int e = (blockIdx.x >> 3) * 256 + threadIdx.x; e < N_EDGES; e += stride) {
        int d = dst[e];
        if (d >= lo && d < hi) {
            int pos = atomicAdd(&cursor[d], 1);
            perm[pos] = e;
        }
    }
}

// kC: gather-build final CSR records (COALESCED writes, random 8B gathers from L2/L3)
__global__ __launch_bounds__(256) void k_build(const int* __restrict__ perm,
                                               const int2* __restrict__ rec_agg,
                                               const uint* __restrict__ ltp,
                                               int2* __restrict__ agg,
                                               int2* __restrict__ dec) {
    int pos = blockIdx.x * 256 + threadIdx.x;
    if (pos >= E_SL) return;
    int p = perm[pos];
    if (p >= N_EDGES) {
        int n = p - N_EDGES;
        agg[pos] = make_int2(n, (int)ltp[0]);
        dec[pos] = make_int2(n, -1);
    } else {
        int2 ra = rec_agg[p];
        agg[pos] = ra;
        dec[pos] = make_int2(ra.x, p);
    }
}

// ---------- K3: layer-0 projection directly from x: xp = x@Wc + bc (encoder folded) ----------
__global__ __launch_bounds__(256) void k_xp0(const float* __restrict__ x,
                                             const float* __restrict__ Wc,
                                             const float* __restrict__ bc,
                                             const float* __restrict__ a_src,
                                             const float* __restrict__ a_dst,
                                             __hip_bfloat16* __restrict__ xpb,
                                             float* __restrict__ s_src,
                                             float* __restrict__ s_dst) {
    __shared__ float w[F_INN * HD];    // 8 KB
    __shared__ float xr[NPB * F_INN];  // 4 KB
    int t = threadIdx.x;
    for (int i = t; i < F_INN * HD / 4; i += 256) ((float4*)w)[i] = ((const float4*)Wc)[i];
    int n0 = blockIdx.x * NPB;
    ((float4*)xr)[t] = ((const float4*)(x + (size_t)n0 * F_INN))[t];   // 256*16B = 4KB exact
    __syncthreads();
    int nl = t >> 6, j = t & 63;
    float asj = a_src[j], adj = a_dst[j], bcj = bc[j];
#pragma unroll
    for (int g = 0; g < NPB / 4; ++g) {
        int node = n0 + g * 4 + nl;
        const float* xrow = &xr[(g * 4 + nl) * F_INN];
        float acc = bcj;
#pragma unroll
        for (int k = 0; k < F_INN; ++k) acc += xrow[k] * w[k * HD + j];
        xpb[(size_t)node * HD + j] = __float2bfloat16(acc);
        float ts = waveReduceSum(acc * asj);
        float td = waveReduceSum(acc * adj);
        if (j == 0) { s_src[node] = ts; s_dst[node] = td; }
    }
}

// ---------- K4: xp(bf16) = h @ W (layer 1), 32 nodes/block ----------
__global__ __launch_bounds__(256) void k_xp(const float* __restrict__ h, const float* __restrict__ W,
                                            const float* __restrict__ a_src, const float* __restrict__ a_dst,
                                            __hip_bfloat16* __restrict__ xpb, float* __restrict__ s_src,
                                            float* __restrict__ s_dst) {
    __shared__ float w[HD * HD];     // 16 KB
    __shared__ float hr[NPB * HD];   // 8 KB
    int t = threadIdx.x;
    for (int i = t; i < HD * HD / 4; i += 256) ((float4*)w)[i] = ((const float4*)W)[i];
    int n0 = blockIdx.x * NPB;
    for (int i = t; i < NPB * HD / 4; i += 256)
        ((float4*)hr)[i] = ((const float4*)(h + (size_t)n0 * HD))[i];
    __syncthreads();
    int nl = t >> 6, j = t & 63;
    float asj = a_src[j], adj = a_dst[j];
#pragma unroll
    for (int g = 0; g < NPB / 4; ++g) {
        int node = n0 + g * 4 + nl;
        const float* hrow = &hr[(g * 4 + nl) * HD];
        float acc = 0.0f;
#pragma unroll
        for (int k = 0; k < HD; ++k) acc += hrow[k] * w[k * HD + j];
        xpb[(size_t)node * HD + j] = __float2bfloat16(acc);
        float ts = waveReduceSum(acc * asj);
        float td = waveReduceSum(acc * adj);
        if (j == 0) { s_src[node] = ts; s_dst[node] = td; }
    }
}

// ---------- K5: gather-aggregate — wave/node, 16-lane groups, 8 edges/iter in flight ----------
template <int LAYER>
__global__ __launch_bounds__(256) void k_aggregate(const int* __restrict__ row_ptr,
                                                   const int2* __restrict__ agg,
                                                   const float* __restrict__ s_src,
                                                   const float* __restrict__ s_dst,
                                                   const uint2* __restrict__ xpr,   // bf16 x4 per lane
                                                   const float* __restrict__ bias,
                                                   float* __restrict__ h) {
    int t = threadIdx.x;
    int node = blockIdx.x * 4 + (t >> 6);    // grid exact: N/4
    int lane = t & 63;
    int g = lane >> 4, li = lane & 15;
    int start = row_ptr[node], end = row_ptr[node + 1];
    float sd = s_dst[node];
    float ax = 0.0f, ay = 0.0f, az = 0.0f, aw = 0.0f, den = 0.0f;
    int i = start;
    for (; i + 8 <= end; i += 8) {
        int2 r0 = agg[i + g];
        int2 r1 = agg[i + 4 + g];
        int sp0 = r0.x, sp1 = r1.x;
        uint2 u0 = xpr[(size_t)sp0 * 16 + li];
        uint2 u1 = xpr[(size_t)sp1 * 16 + li];
        float a0 = s_src[sp0] + sd + (LAYER == 0 ? bf_lo((uint)r0.y) : bf_hi((uint)r0.y));
        float a1 = s_src[sp1] + sd + (LAYER == 0 ? bf_lo((uint)r1.y) : bf_hi((uint)r1.y));
        a0 = a0 > 0.0f ? a0 : NEG_SLOPE * a0;
        a1 = a1 > 0.0f ? a1 : NEG_SLOPE * a1;
        float ex0 = __expf(a0), ex1 = __expf(a1);
        den += ex0 + ex1;
        ax += ex0 * bf_lo(u0.x) + ex1 * bf_lo(u1.x);
        ay += ex0 * bf_hi(u0.x) + ex1 * bf_hi(u1.x);
        az += ex0 * bf_lo(u0.y) + ex1 * bf_lo(u1.y);
        aw += ex0 * bf_hi(u0.y) + ex1 * bf_hi(u1.y);
    }
    for (; i < end; i += 4) {
        int idx = i + g;
        bool valid = idx < end;
        int2 r = agg[valid ? idx : end - 1];
        int sp = r.x;
        uint2 u = xpr[(size_t)sp * 16 + li];
        float a = s_src[sp] + sd + (LAYER == 0 ? bf_lo((uint)r.y) : bf_hi((uint)r.y));
        a = a > 0.0f ? a : NEG_SLOPE * a;
        float ex = valid ? __expf(a) : 0.0f;
        den += ex;
        ax += ex * bf_lo(u.x);
        ay += ex * bf_hi(u.x);
        az += ex * bf_lo(u.y);
        aw += ex * bf_hi(u.y);
    }
    // cross-group reduce (4 groups -> group 0)
    den += __shfl_down(den, 32, 64); ax += __shfl_down(ax, 32, 64);
    ay  += __shfl_down(ay, 32, 64); az += __shfl_down(az, 32, 64);
    aw  += __shfl_down(aw, 32, 64);
    den += __shfl_down(den, 16, 64); ax += __shfl_down(ax, 16, 64);
    ay  += __shfl_down(ay, 16, 64); az += __shfl_down(az, 16, 64);
    aw  += __shfl_down(aw, 16, 64);
    if (lane < 16) {
        float inv = 1.0f / (den + 1e-16f);
        float4 b4 = ((const float4*)bias)[li];
        float4 v;
        v.x = fmaxf(ax * inv + b4.x, 0.0f);
        v.y = fmaxf(ay * inv + b4.y, 0.0f);
        v.z = fmaxf(az * inv + b4.z, 0.0f);
        v.w = fmaxf(aw * inv + b4.w, 0.0f);
        ((float4*)(h + (size_t)node * HD))[li] = v;
    }
}

// ---------- K6: u1(bf16)=h@W1a, u2(f32)=h@W1b, 32 nodes/block (u2 aliases h: LDS-read first) ----------
__global__ __launch_bounds__(256) void k_umm(const float* __restrict__ h, const float* __restrict__ w1,
                                             __hip_bfloat16* __restrict__ u1b, float* __restrict__ u2) {
    __shared__ float w[2 * HD * HD];   // 32 KB
    __shared__ float hr[NPB * HD];     // 8 KB
    int t = threadIdx.x;
    for (int i = t; i < 2 * HD * HD / 4; i += 256) ((float4*)w)[i] = ((const float4*)w1)[i];
    int n0 = blockIdx.x * NPB;
    for (int i = t; i < NPB * HD / 4; i += 256)
        ((float4*)hr)[i] = ((const float4*)(h + (size_t)n0 * HD))[i];
    __syncthreads();
    int nl = t >> 6, j = t & 63;
#pragma unroll
    for (int g = 0; g < NPB / 4; ++g) {
        int node = n0 + g * 4 + nl;
        const float* hrow = &hr[(g * 4 + nl) * HD];
        float a1 = 0.0f, a2 = 0.0f;
#pragma unroll
        for (int k = 0; k < HD; ++k) {
            float hk = hrow[k];
            a1 += hk * w[k * HD + j];
            a2 += hk * w[(HD + k) * HD + j];
        }
        u1b[(size_t)node * HD + j] = __float2bfloat16(a1);
        u2[(size_t)node * HD + j] = a2;
    }
}

// ---------- K7: CSR decode — wave/node, 16-lane groups, 8 edges/iter, width-16 reduce ----------
__global__ __launch_bounds__(256) void k_decode_csr(const int* __restrict__ row_ptr,
                                                    const int2* __restrict__ dec,
                                                    const uint2* __restrict__ u1r,  // bf16 x4 per lane
                                                    const float* __restrict__ u2,
                                                    const float* __restrict__ b1,
                                                    const float* __restrict__ w2,
                                                    const float* __restrict__ b2,
                                                    float* __restrict__ out) {
    int t = threadIdx.x;
    int node = blockIdx.x * 4 + (t >> 6);    // grid exact: N/4
    int lane = t & 63;
    int g = lane >> 4, li = lane & 15;
    float4 c4 = ((const float4*)(u2 + (size_t)node * HD))[li];
    float4 b14 = ((const float4*)b1)[li];
    float4 w4 = ((const float4*)w2)[li];
    c4.x += b14.x; c4.y += b14.y; c4.z += b14.z; c4.w += b14.w;
    float bb = b2[0];
    int start = row_ptr[node], end = row_ptr[node + 1];
    int i = start;
    for (; i + 8 <= end; i += 8) {
        int2 e0 = dec[i + g];
        int2 e1 = dec[i + 4 + g];
        uint2 ua = u1r[(size_t)e0.x * 16 + li];
        uint2 ub = u1r[(size_t)e1.x * 16 + li];
        float p0 = fmaxf(bf_lo(ua.x) + c4.x, 0.0f) * w4.x
                 + fmaxf(bf_hi(ua.x) + c4.y, 0.0f) * w4.y
                 + fmaxf(bf_lo(ua.y) + c4.z, 0.0f) * w4.z
                 + fmaxf(bf_hi(ua.y) + c4.w, 0.0f) * w4.w;
        float p1 = fmaxf(bf_lo(ub.x) + c4.x, 0.0f) * w4.x
                 + fmaxf(bf_hi(ub.x) + c4.y, 0.0f) * w4.y
                 + fmaxf(bf_lo(ub.y) + c4.z, 0.0f) * w4.z
                 + fmaxf(bf_hi(ub.y) + c4.w, 0.0f) * w4.w;
#pragma unroll
        for (int off = 8; off > 0; off >>= 1) {
            p0 += __shfl_down(p0, off, 16);
            p1 += __shfl_down(p1, off, 16);
        }
        if (li == 0) {
            if (e0.y >= 0) out[e0.y] = 1.0f / (1.0f + __expf(-(p0 + bb)));
            if (e1.y >= 0) out[e1.y] = 1.0f / (1.0f + __expf(-(p1 + bb)));
        }
    }
    for (; i < end; i += 4) {
        int idx = i + g;
        bool valid = idx < end;
        int2 e = dec[valid ? idx : end - 1];
        uint2 u = u1r[(size_t)e.x * 16 + li];
        float p = fmaxf(bf_lo(u.x) + c4.x, 0.0f) * w4.x
                + fmaxf(bf_hi(u.x) + c4.y, 0.0f) * w4.y
                + fmaxf(bf_lo(u.y) + c4.z, 0.0f) * w4.z
                + fmaxf(bf_hi(u.y) + c4.w, 0.0f) * w4.w;
#pragma unroll
        for (int off = 8; off > 0; off >>= 1) p += __shfl_down(p, off, 16);
        if (li == 0 && valid && e.y >= 0)
            out[e.y] = 1.0f / (1.0f + __expf(-(p + bb)));
    }
}

extern "C" void kernel_launch(void* const* d_in, const int* in_sizes, int n_in,
                              void* d_out, int out_size, void* d_ws, size_t ws_size,
                              hipStream_t stream) {
    const float* x        = (const float*)d_in[0];
    const int*   eidx     = (const int*)d_in[1];
    const float* eattr    = (const float*)d_in[2];
    const float* enc_w    = (const float*)d_in[3];
    const float* enc_b    = (const float*)d_in[4];
    const float* gat_w    = (const float*)d_in[5];
    const float* att_src  = (const float*)d_in[6];
    const float* att_dst  = (const float*)d_in[7];
    const float* edge_w   = (const float*)d_in[8];
    const float* att_edge = (const float*)d_in[9];
    const float* gat_b    = (const float*)d_in[10];
    const float* lp_w1    = (const float*)d_in[11];
    const float* lp_b1    = (const float*)d_in[12];
    const float* lp_w2    = (const float*)d_in[13];
    const float* lp_b2    = (const float*)d_in[14];
    float* out = (float*)d_out;

    const int* src = eidx;
    const int* dst = eidx + N_EDGES;

    // ---- workspace layout ----
    float* ws = (float*)d_ws;
    float*  h       = ws;                                   // N*64 f32 (u2 after k_umm)
    int2*   rec_agg = (int2*)h;                             // E int2 (alias; dead before aggregate<0>)
    int*    perm    = (int*)(rec_agg + N_EDGES);            // E_SL int (alias)
    __hip_bfloat16* xpb = (__hip_bfloat16*)(h + (size_t)N_NODES * HD);  // N*64 bf16 (u1b after k_umm)
    int2*   agg     = (int2*)((char*)xpb + (size_t)N_NODES * HD * 2);   // E_SL int2 (13.6MB)
    int2*   dec     = agg + E_SL;                           // E_SL int2 (13.6MB)
    float*  fsmall    = (float*)(dec + E_SL);
    float*  s_src     = fsmall;                             // N
    float*  s_dst     = s_src + N_NODES;                    // N
    float*  partials  = s_dst + N_NODES;                    // MEAN_BLOCKS*4*8
    float*  we_vec    = partials + MEAN_BLOCKS * 4 * 8;     // 16
    uint*   ltp       = (uint*)(we_vec + 16);               // 1
    float*  Wc        = (float*)(ltp + 1);                  // 32*64
    float*  bc        = Wc + F_INN * HD;                    // 64
    int*    row_ptr   = (int*)(bc + HD);                    // N+1
    int*    cursor    = row_ptr + N_NODES + 1;              // N
    int*    deg       = cursor + N_NODES;                   // N
    int*    blk_sums  = deg + N_NODES;                      // N_SCAN_BLOCKS
    int*    blk_off   = blk_sums + N_SCAN_BLOCKS;           // N_SCAN_BLOCKS

    const int NB_N256 = (N_NODES + 255) / 256;   // 391
    const int NB_EDGE = (E_SL + 255) / 256;      // 6641
    const int NB_AGG  = N_NODES / 4;             // 25000
    const int NB_DENSE = N_NODES / NPB;          // 3125

    // small precomputes + edge-ordered records
    k_init_small<<<1, 64, 0, stream>>>(edge_w, att_edge, we_vec);
    k_fuse_w<<<1, 256, 0, stream>>>(enc_w, enc_b, gat_w, Wc, bc);
    k_mean_edterm<<<MEAN_BLOCKS, 256, 0, stream>>>(eattr, src, we_vec, partials, rec_agg);
    k_mean_final<<<1, 256, 0, stream>>>(partials, we_vec, ltp);

    // CSR build: hist -> scan -> perm scatter (XCD-sharded) -> coalesced record build
    k_deg_init<<<NB_N256, 256, 0, stream>>>(deg);
    k_hist<<<N_EDGES / 256, 256, 0, stream>>>(dst, deg);
    k_scan1<<<N_SCAN_BLOCKS, SCAN_BLOCK, 0, stream>>>(deg, row_ptr, blk_sums);
    k_scan2<<<1, 256, 0, stream>>>(blk_sums, blk_off);
    k_scan3<<<NB_N256, 256, 0, stream>>>(row_ptr, blk_off, deg, cursor, perm);
    k_perm_scatter<<<PERM_BLOCKS, 256, 0, stream>>>(dst, cursor, perm);
    k_build<<<NB_EDGE, 256, 0, stream>>>(perm, rec_agg, ltp, agg, dec);

    // layer-0 projection (encoder folded into Wc/bc)
    k_xp0<<<NB_DENSE, 256, 0, stream>>>(x, Wc, bc, att_src, att_dst, xpb, s_src, s_dst);
    k_aggregate<0><<<NB_AGG, 256, 0, stream>>>(row_ptr, agg, s_src, s_dst,
                                               (const uint2*)xpb, gat_b, h);
    // GAT layer 1
    k_xp<<<NB_DENSE, 256, 0, stream>>>(h, gat_w + HD * HD, att_src + HD, att_dst + HD,
                                       xpb, s_src, s_dst);
    k_aggregate<1><<<NB_AGG, 256, 0, stream>>>(row_ptr, agg, s_src, s_dst,
                                               (const uint2*)xpb, gat_b + HD, h);

    // decoder: u1(bf16) -> xpb buffer, u2(fp32) -> h buffer
    k_umm<<<NB_DENSE, 256, 0, stream>>>(h, lp_w1, xpb, h);
    k_decode_csr<<<NB_AGG, 256, 0, stream>>>(row_ptr, dec, (const uint2*)xpb, h,
                                             lp_b1, lp_w2, lp_b2, out);
}

// Round 11
// 587.811 us; speedup vs baseline: 1.5442x; 1.5442x over previous
//
#include <hip/hip_runtime.h>
#include <hip/hip_bf16.h>
#include <math.h>

#define N_NODES 100000
#define N_EDGES 1600000
#define F_INN   32
#define F_EE    8
#define HD      64
#define E_SL    (N_EDGES + N_NODES)   // edges + self loops
#define NEG_SLOPE 0.2f
#define MEAN_BLOCKS 256
#define SCAN_BLOCK 512
#define N_SCAN_BLOCKS ((N_NODES + SCAN_BLOCK - 1) / SCAN_BLOCK)   // 196
#define SHARD_W (N_NODES / 8)         // 12500 nodes per XCD shard
#define PERM_BLOCKS 2048              // 256 blocks per shard
#define NPB 32                        // nodes per block in dense kernels (3125 blocks)

// ---------- helpers ----------
__device__ __forceinline__ float waveReduceSum(float v) {
#pragma unroll
    for (int off = 32; off > 0; off >>= 1) v += __shfl_down(v, off, 64);
    return v;
}
__device__ __forceinline__ float bf_lo(uint u) { return __uint_as_float(u << 16); }
__device__ __forceinline__ float bf_hi(uint u) { return __uint_as_float(u & 0xffff0000u); }
__device__ __forceinline__ uint pack_bf2(float a, float b) {
    __hip_bfloat16 ha = __float2bfloat16(a), hb = __float2bfloat16(b);
    unsigned short ua, ub;
    __builtin_memcpy(&ua, &ha, 2); __builtin_memcpy(&ub, &hb, 2);
    return (uint)ua | ((uint)ub << 16);
}

// ---------- K1: we_vec[l][k] = dot(edge_w[l][k,:], att_edge[l,:]) ----------
__global__ void k_init_small(const float* __restrict__ edge_w, const float* __restrict__ att_edge,
                             float* __restrict__ we_vec) {
    int t = threadIdx.x;
    if (t < 16) {
        int l = t >> 3, k = t & 7;
        const float* We = edge_w + l * F_EE * HD + k * HD;
        const float* ae = att_edge + l * HD;
        float s = 0.0f;
#pragma unroll
        for (int j = 0; j < HD; ++j) s += We[j] * ae[j];
        we_vec[l * 8 + k] = s;
    }
}

// ---------- K1b: fold encoder into layer-0 projection: Wc = enc_w@W0, bc = enc_b@W0 ----------
__global__ __launch_bounds__(256) void k_fuse_w(const float* __restrict__ enc_w,
                                                const float* __restrict__ enc_b,
                                                const float* __restrict__ W0,
                                                float* __restrict__ Wc, float* __restrict__ bc) {
    int t = threadIdx.x;
    for (int idx = t; idx < F_INN * HD; idx += 256) {
        int r = idx >> 6, c = idx & 63;
        float s = 0.0f;
#pragma unroll
        for (int k = 0; k < HD; ++k) s += enc_w[r * HD + k] * W0[k * HD + c];
        Wc[idx] = s;
    }
    if (t < HD) {
        float s = 0.0f;
#pragma unroll
        for (int k = 0; k < HD; ++k) s += enc_b[k] * W0[k * HD + t];
        bc[t] = s;
    }
}

// ---------- K2a: fused — mean partials AND edge-ordered records {src, packed bf16 ed01} ----------
__global__ __launch_bounds__(256) void k_mean_edterm(const float* __restrict__ eattr,
                                                     const int* __restrict__ src,
                                                     const float* __restrict__ we_vec,
                                                     float* __restrict__ partials,
                                                     int2* __restrict__ rec_agg) {
    __shared__ float sw[16];
    int t = threadIdx.x;
    if (t < 16) sw[t] = we_vec[t];
    __syncthreads();
    float p[8];
#pragma unroll
    for (int k = 0; k < 8; ++k) p[k] = 0.0f;
    for (int e = blockIdx.x * blockDim.x + t; e < N_EDGES; e += gridDim.x * blockDim.x) {
        const float4* row = (const float4*)(eattr + (size_t)e * F_EE);
        float4 r0 = row[0], r1 = row[1];
        p[0] += r0.x; p[1] += r0.y; p[2] += r0.z; p[3] += r0.w;
        p[4] += r1.x; p[5] += r1.y; p[6] += r1.z; p[7] += r1.w;
        float ed0 = r0.x * sw[0] + r0.y * sw[1] + r0.z * sw[2] + r0.w * sw[3]
                  + r1.x * sw[4] + r1.y * sw[5] + r1.z * sw[6] + r1.w * sw[7];
        float ed1 = r0.x * sw[8] + r0.y * sw[9] + r0.z * sw[10] + r0.w * sw[11]
                  + r1.x * sw[12] + r1.y * sw[13] + r1.z * sw[14] + r1.w * sw[15];
        rec_agg[e] = make_int2(src[e], (int)pack_bf2(ed0, ed1));
    }
#pragma unroll
    for (int k = 0; k < 8; ++k) p[k] = waveReduceSum(p[k]);
    int wave = t >> 6;
    if ((t & 63) == 0) {
        float* dstp = partials + ((size_t)blockIdx.x * 4 + wave) * 8;
#pragma unroll
        for (int k = 0; k < 8; ++k) dstp[k] = p[k];
    }
}

// ---------- K2b: finish mean; ltp = packed bf16 {loop_term0, loop_term1} ----------
__global__ __launch_bounds__(256) void k_mean_final(const float* __restrict__ partials,
                                                    const float* __restrict__ we_vec,
                                                    uint* __restrict__ ltp) {
    __shared__ float red[256];
    __shared__ float mean8[8];
    __shared__ float lt[2];
    int t = threadIdx.x;
    int k = t & 7;
    int chunk = t >> 3;
    float s = 0.0f;
    for (int i = chunk; i < MEAN_BLOCKS * 4; i += 32) s += partials[(size_t)i * 8 + k];
    red[t] = s;
    __syncthreads();
    if (t < 8) {
        float acc = 0.0f;
#pragma unroll
        for (int c = 0; c < 32; ++c) acc += red[c * 8 + t];
        mean8[t] = acc * (1.0f / N_EDGES);
    }
    __syncthreads();
    if (t < 2) {
        float acc = 0.0f;
#pragma unroll
        for (int kk = 0; kk < 8; ++kk) acc += mean8[kk] * we_vec[t * 8 + kk];
        lt[t] = acc;
    }
    __syncthreads();
    if (t == 0) ltp[0] = pack_bf2(lt[0], lt[1]);
}

// ---------- CSR build ----------
__global__ void k_deg_init(int* __restrict__ deg) {
    int i = blockIdx.x * 256 + threadIdx.x;
    if (i < N_NODES) deg[i] = 1;   // self-loop
}

__global__ void k_hist(const int* __restrict__ dst, int* __restrict__ deg) {
    int e = blockIdx.x * 256 + threadIdx.x;   // grid exact: E/256
    atomicAdd(&deg[dst[e]], 1);
}

__global__ __launch_bounds__(SCAN_BLOCK) void k_scan1(const int* __restrict__ deg,
                                                      int* __restrict__ row_ptr,
                                                      int* __restrict__ blk_sums) {
    __shared__ int sd[SCAN_BLOCK];
    int t = threadIdx.x;
    int i = blockIdx.x * SCAN_BLOCK + t;
    int v = (i < N_NODES) ? deg[i] : 0;
    sd[t] = v;
    for (int off = 1; off < SCAN_BLOCK; off <<= 1) {
        __syncthreads();
        int x = (t >= off) ? sd[t - off] : 0;
        __syncthreads();
        sd[t] += x;
    }
    __syncthreads();
    if (i < N_NODES) row_ptr[i] = sd[t] - v;
    if (t == SCAN_BLOCK - 1) blk_sums[blockIdx.x] = sd[t];
}

__global__ __launch_bounds__(256) void k_scan2(int* __restrict__ blk_sums,
                                               int* __restrict__ blk_off) {
    __shared__ int sd[256];
    int t = threadIdx.x;
    int v = (t < N_SCAN_BLOCKS) ? blk_sums[t] : 0;
    sd[t] = v;
    for (int off = 1; off < 256; off <<= 1) {
        __syncthreads();
        int x = (t >= off) ? sd[t - off] : 0;
        __syncthreads();
        sd[t] += x;
    }
    __syncthreads();
    if (t < N_SCAN_BLOCKS) blk_off[t] = sd[t] - v;
}

// finalize row_ptr, init cursor, and drop self-loop marker into the LAST slot of each segment
__global__ void k_scan3(int* __restrict__ row_ptr, const int* __restrict__ blk_off,
                        const int* __restrict__ deg,
                        int* __restrict__ cursor, int* __restrict__ perm) {
    int i = blockIdx.x * 256 + threadIdx.x;
    if (i < N_NODES) {
        int r = row_ptr[i] + blk_off[i / SCAN_BLOCK];
        row_ptr[i] = r;
        cursor[i] = r;
        perm[r + deg[i] - 1] = N_EDGES + i;   // self-loop marker
    }
    if (i == 0) row_ptr[N_NODES] = E_SL;
}

// kB: XCD-sharded perm scatter
__global__ __launch_bounds__(256) void k_perm_scatter(const int* __restrict__ dst,
                                                      int* __restrict__ cursor,
                                                      int* __restrict__ perm) {
    int shard = blockIdx.x & 7;
    int lo = shard * SHARD_W, hi = lo + SHARD_W;
    int stride = (PERM_BLOCKS >> 3) * 256;
    for (int e = (blockIdx.x >> 3) * 256 + threadIdx.x; e < N_EDGES; e += stride) {
        int d = dst[e];
        if (d >= lo && d < hi) {
            int pos = atomicAdd(&cursor[d], 1);
            perm[pos] = e;
        }
    }
}

// kC: gather-build final CSR records (coalesced writes)
__global__ __launch_bounds__(256) void k_build(const int* __restrict__ perm,
                                               const int2* __restrict__ rec_agg,
                                               const uint* __restrict__ ltp,
                                               int2* __restrict__ agg,
                                               int2* __restrict__ dec) {
    int pos = blockIdx.x * 256 + threadIdx.x;
    if (pos >= E_SL) return;
    int p = perm[pos];
    if (p >= N_EDGES) {
        int n = p - N_EDGES;
        agg[pos] = make_int2(n, (int)ltp[0]);
        dec[pos] = make_int2(n, -1);
    } else {
        int2 ra = rec_agg[p];
        agg[pos] = ra;
        dec[pos] = make_int2(ra.x, p);
    }
}

// ---------- K3: layer-0 projection xp = x@Wc + bc — weight column in VGPRs, x broadcast via LDS ----------
__global__ __launch_bounds__(256) void k_xp0(const float* __restrict__ x,
                                             const float* __restrict__ Wc,
                                             const float* __restrict__ bc,
                                             const float* __restrict__ a_src,
                                             const float* __restrict__ a_dst,
                                             __hip_bfloat16* __restrict__ xpb,
                                             float* __restrict__ s_src,
                                             float* __restrict__ s_dst) {
    __shared__ float xr[NPB * F_INN];  // 4 KB
    int t = threadIdx.x;
    int j = t & 63, wv = t >> 6;
    float4 w[F_INN / 4];               // 8 VGPR float4s = weight column j
#pragma unroll
    for (int kk = 0; kk < F_INN / 4; ++kk) {
        w[kk].x = Wc[(4 * kk + 0) * HD + j];
        w[kk].y = Wc[(4 * kk + 1) * HD + j];
        w[kk].z = Wc[(4 * kk + 2) * HD + j];
        w[kk].w = Wc[(4 * kk + 3) * HD + j];
    }
    int n0 = blockIdx.x * NPB;
    ((float4*)xr)[t] = ((const float4*)(x + (size_t)n0 * F_INN))[t];  // 256*16B = 4KB exact
    __syncthreads();
    float asj = a_src[j], adj = a_dst[j], bcj = bc[j];
    for (int n = wv; n < NPB; n += 4) {
        const float4* hx = (const float4*)&xr[n * F_INN];
        float acc = bcj;
#pragma unroll
        for (int kk = 0; kk < F_INN / 4; ++kk) {
            float4 hv = hx[kk];   // wave-uniform broadcast ds_read_b128
            acc += hv.x * w[kk].x + hv.y * w[kk].y + hv.z * w[kk].z + hv.w * w[kk].w;
        }
        int node = n0 + n;
        xpb[(size_t)node * HD + j] = __float2bfloat16(acc);
        float ts = waveReduceSum(acc * asj);
        float td = waveReduceSum(acc * adj);
        if (j == 0) { s_src[node] = ts; s_dst[node] = td; }
    }
}

// ---------- K4: xp(bf16) = h @ W (layer 1) — weight column in VGPRs ----------
__global__ __launch_bounds__(256) void k_xp(const float* __restrict__ h, const float* __restrict__ W,
                                            const float* __restrict__ a_src, const float* __restrict__ a_dst,
                                            __hip_bfloat16* __restrict__ xpb, float* __restrict__ s_src,
                                            float* __restrict__ s_dst) {
    __shared__ float hr[NPB * HD];     // 8 KB
    int t = threadIdx.x;
    int j = t & 63, wv = t >> 6;
    float4 w[HD / 4];                  // 16 float4s = 64 VGPRs
#pragma unroll
    for (int kk = 0; kk < HD / 4; ++kk) {
        w[kk].x = W[(4 * kk + 0) * HD + j];
        w[kk].y = W[(4 * kk + 1) * HD + j];
        w[kk].z = W[(4 * kk + 2) * HD + j];
        w[kk].w = W[(4 * kk + 3) * HD + j];
    }
    int n0 = blockIdx.x * NPB;
#pragma unroll
    for (int i = 0; i < 2; ++i)
        ((float4*)hr)[t + i * 256] = ((const float4*)(h + (size_t)n0 * HD))[t + i * 256];
    __syncthreads();
    float asj = a_src[j], adj = a_dst[j];
    for (int n = wv; n < NPB; n += 4) {
        const float4* hx = (const float4*)&hr[n * HD];
        float acc = 0.0f;
#pragma unroll
        for (int kk = 0; kk < HD / 4; ++kk) {
            float4 hv = hx[kk];   // broadcast ds_read_b128
            acc += hv.x * w[kk].x + hv.y * w[kk].y + hv.z * w[kk].z + hv.w * w[kk].w;
        }
        int node = n0 + n;
        xpb[(size_t)node * HD + j] = __float2bfloat16(acc);
        float ts = waveReduceSum(acc * asj);
        float td = waveReduceSum(acc * adj);
        if (j == 0) { s_src[node] = ts; s_dst[node] = td; }
    }
}

// ---------- K5: gather-aggregate — wave/node, 16-lane groups, 8 edges/iter in flight ----------
template <int LAYER>
__global__ __launch_bounds__(256) void k_aggregate(const int* __restrict__ row_ptr,
                                                   const int2* __restrict__ agg,
                                                   const float* __restrict__ s_src,
                                                   const float* __restrict__ s_dst,
                                                   const uint2* __restrict__ xpr,   // bf16 x4 per lane
                                                   const float* __restrict__ bias,
                                                   float* __restrict__ h) {
    int t = threadIdx.x;
    int node = blockIdx.x * 4 + (t >> 6);    // grid exact: N/4
    int lane = t & 63;
    int g = lane >> 4, li = lane & 15;
    int start = row_ptr[node], end = row_ptr[node + 1];
    float sd = s_dst[node];
    float ax = 0.0f, ay = 0.0f, az = 0.0f, aw = 0.0f, den = 0.0f;
    int i = start;
    for (; i + 8 <= end; i += 8) {
        int2 r0 = agg[i + g];
        int2 r1 = agg[i + 4 + g];
        int sp0 = r0.x, sp1 = r1.x;
        uint2 u0 = xpr[(size_t)sp0 * 16 + li];
        uint2 u1 = xpr[(size_t)sp1 * 16 + li];
        float a0 = s_src[sp0] + sd + (LAYER == 0 ? bf_lo((uint)r0.y) : bf_hi((uint)r0.y));
        float a1 = s_src[sp1] + sd + (LAYER == 0 ? bf_lo((uint)r1.y) : bf_hi((uint)r1.y));
        a0 = a0 > 0.0f ? a0 : NEG_SLOPE * a0;
        a1 = a1 > 0.0f ? a1 : NEG_SLOPE * a1;
        float ex0 = __expf(a0), ex1 = __expf(a1);
        den += ex0 + ex1;
        ax += ex0 * bf_lo(u0.x) + ex1 * bf_lo(u1.x);
        ay += ex0 * bf_hi(u0.x) + ex1 * bf_hi(u1.x);
        az += ex0 * bf_lo(u0.y) + ex1 * bf_lo(u1.y);
        aw += ex0 * bf_hi(u0.y) + ex1 * bf_hi(u1.y);
    }
    for (; i < end; i += 4) {
        int idx = i + g;
        bool valid = idx < end;
        int2 r = agg[valid ? idx : end - 1];
        int sp = r.x;
        uint2 u = xpr[(size_t)sp * 16 + li];
        float a = s_src[sp] + sd + (LAYER == 0 ? bf_lo((uint)r.y) : bf_hi((uint)r.y));
        a = a > 0.0f ? a : NEG_SLOPE * a;
        float ex = valid ? __expf(a) : 0.0f;
        den += ex;
        ax += ex * bf_lo(u.x);
        ay += ex * bf_hi(u.x);
        az += ex * bf_lo(u.y);
        aw += ex * bf_hi(u.y);
    }
    den += __shfl_down(den, 32, 64); ax += __shfl_down(ax, 32, 64);
    ay  += __shfl_down(ay, 32, 64); az += __shfl_down(az, 32, 64);
    aw  += __shfl_down(aw, 32, 64);
    den += __shfl_down(den, 16, 64); ax += __shfl_down(ax, 16, 64);
    ay  += __shfl_down(ay, 16, 64); az += __shfl_down(az, 16, 64);
    aw  += __shfl_down(aw, 16, 64);
    if (lane < 16) {
        float inv = 1.0f / (den + 1e-16f);
        float4 b4 = ((const float4*)bias)[li];
        float4 v;
        v.x = fmaxf(ax * inv + b4.x, 0.0f);
        v.y = fmaxf(ay * inv + b4.y, 0.0f);
        v.z = fmaxf(az * inv + b4.z, 0.0f);
        v.w = fmaxf(aw * inv + b4.w, 0.0f);
        ((float4*)(h + (size_t)node * HD))[li] = v;
    }
}

// ---------- K6: u1(bf16)=h@W1a, u2(f32)=h@W1b — both weight columns in VGPRs ----------
// (u2 aliases h: tile staged to LDS before any write)
__global__ __launch_bounds__(256) void k_umm(const float* __restrict__ h, const float* __restrict__ w1,
                                             __hip_bfloat16* __restrict__ u1b, float* __restrict__ u2) {
    __shared__ float hr[NPB * HD];     // 8 KB
    int t = threadIdx.x;
    int j = t & 63, wv = t >> 6;
    float4 wa[HD / 4], wb[HD / 4];     // 128 VGPRs
#pragma unroll
    for (int kk = 0; kk < HD / 4; ++kk) {
        wa[kk].x = w1[(4 * kk + 0) * HD + j];
        wa[kk].y = w1[(4 * kk + 1) * HD + j];
        wa[kk].z = w1[(4 * kk + 2) * HD + j];
        wa[kk].w = w1[(4 * kk + 3) * HD + j];
        wb[kk].x = w1[(HD + 4 * kk + 0) * HD + j];
        wb[kk].y = w1[(HD + 4 * kk + 1) * HD + j];
        wb[kk].z = w1[(HD + 4 * kk + 2) * HD + j];
        wb[kk].w = w1[(HD + 4 * kk + 3) * HD + j];
    }
    int n0 = blockIdx.x * NPB;
#pragma unroll
    for (int i = 0; i < 2; ++i)
        ((float4*)hr)[t + i * 256] = ((const float4*)(h + (size_t)n0 * HD))[t + i * 256];
    __syncthreads();
    for (int n = wv; n < NPB; n += 4) {
        const float4* hx = (const float4*)&hr[n * HD];
        float a1 = 0.0f, a2 = 0.0f;
#pragma unroll
        for (int kk = 0; kk < HD / 4; ++kk) {
            float4 hv = hx[kk];   // broadcast ds_read_b128
            a1 += hv.x * wa[kk].x + hv.y * wa[kk].y + hv.z * wa[kk].z + hv.w * wa[kk].w;
            a2 += hv.x * wb[kk].x + hv.y * wb[kk].y + hv.z * wb[kk].z + hv.w * wb[kk].w;
        }
        int node = n0 + n;
        u1b[(size_t)node * HD + j] = __float2bfloat16(a1);
        u2[(size_t)node * HD + j] = a2;
    }
}

// ---------- K7: CSR decode — wave/node, 16-lane groups, 8 edges/iter, width-16 reduce ----------
__global__ __launch_bounds__(256) void k_decode_csr(const int* __restrict__ row_ptr,
                                                    const int2* __restrict__ dec,
                                                    const uint2* __restrict__ u1r,  // bf16 x4 per lane
                                                    const float* __restrict__ u2,
                                                    const float* __restrict__ b1,
                                                    const float* __restrict__ w2,
                                                    const float* __restrict__ b2,
                                                    float* __restrict__ out) {
    int t = threadIdx.x;
    int node = blockIdx.x * 4 + (t >> 6);    // grid exact: N/4
    int lane = t & 63;
    int g = lane >> 4, li = lane & 15;
    float4 c4 = ((const float4*)(u2 + (size_t)node * HD))[li];
    float4 b14 = ((const float4*)b1)[li];
    float4 w4 = ((const float4*)w2)[li];
    c4.x += b14.x; c4.y += b14.y; c4.z += b14.z; c4.w += b14.w;
    float bb = b2[0];
    int start = row_ptr[node], end = row_ptr[node + 1];
    int i = start;
    for (; i + 8 <= end; i += 8) {
        int2 e0 = dec[i + g];
        int2 e1 = dec[i + 4 + g];
        uint2 ua = u1r[(size_t)e0.x * 16 + li];
        uint2 ub = u1r[(size_t)e1.x * 16 + li];
        float p0 = fmaxf(bf_lo(ua.x) + c4.x, 0.0f) * w4.x
                 + fmaxf(bf_hi(ua.x) + c4.y, 0.0f) * w4.y
                 + fmaxf(bf_lo(ua.y) + c4.z, 0.0f) * w4.z
                 + fmaxf(bf_hi(ua.y) + c4.w, 0.0f) * w4.w;
        float p1 = fmaxf(bf_lo(ub.x) + c4.x, 0.0f) * w4.x
                 + fmaxf(bf_hi(ub.x) + c4.y, 0.0f) * w4.y
                 + fmaxf(bf_lo(ub.y) + c4.z, 0.0f) * w4.z
                 + fmaxf(bf_hi(ub.y) + c4.w, 0.0f) * w4.w;
#pragma unroll
        for (int off = 8; off > 0; off >>= 1) {
            p0 += __shfl_down(p0, off, 16);
            p1 += __shfl_down(p1, off, 16);
        }
        if (li == 0) {
            if (e0.y >= 0) out[e0.y] = 1.0f / (1.0f + __expf(-(p0 + bb)));
            if (e1.y >= 0) out[e1.y] = 1.0f / (1.0f + __expf(-(p1 + bb)));
        }
    }
    for (; i < end; i += 4) {
        int idx = i + g;
        bool valid = idx < end;
        int2 e = dec[valid ? idx : end - 1];
        uint2 u = u1r[(size_t)e.x * 16 + li];
        float p = fmaxf(bf_lo(u.x) + c4.x, 0.0f) * w4.x
                + fmaxf(bf_hi(u.x) + c4.y, 0.0f) * w4.y
                + fmaxf(bf_lo(u.y) + c4.z, 0.0f) * w4.z
                + fmaxf(bf_hi(u.y) + c4.w, 0.0f) * w4.w;
#pragma unroll
        for (int off = 8; off > 0; off >>= 1) p += __shfl_down(p, off, 16);
        if (li == 0 && valid && e.y >= 0)
            out[e.y] = 1.0f / (1.0f + __expf(-(p + bb)));
    }
}

extern "C" void kernel_launch(void* const* d_in, const int* in_sizes, int n_in,
                              void* d_out, int out_size, void* d_ws, size_t ws_size,
                              hipStream_t stream) {
    const float* x        = (const float*)d_in[0];
    const int*   eidx     = (const int*)d_in[1];
    const float* eattr    = (const float*)d_in[2];
    const float* enc_w    = (const float*)d_in[3];
    const float* enc_b    = (const float*)d_in[4];
    const float* gat_w    = (const float*)d_in[5];
    const float* att_src  = (const float*)d_in[6];
    const float* att_dst  = (const float*)d_in[7];
    const float* edge_w   = (const float*)d_in[8];
    const float* att_edge = (const float*)d_in[9];
    const float* gat_b    = (const float*)d_in[10];
    const float* lp_w1    = (const float*)d_in[11];
    const float* lp_b1    = (const float*)d_in[12];
    const float* lp_w2    = (const float*)d_in[13];
    const float* lp_b2    = (const float*)d_in[14];
    float* out = (float*)d_out;

    const int* src = eidx;
    const int* dst = eidx + N_EDGES;

    // ---- workspace layout ----
    float* ws = (float*)d_ws;
    float*  h       = ws;                                   // N*64 f32 (u2 after k_umm)
    int2*   rec_agg = (int2*)h;                             // E int2 (alias; dead before aggregate<0>)
    int*    perm    = (int*)(rec_agg + N_EDGES);            // E_SL int (alias)
    __hip_bfloat16* xpb = (__hip_bfloat16*)(h + (size_t)N_NODES * HD);  // N*64 bf16 (u1b after k_umm)
    int2*   agg     = (int2*)((char*)xpb + (size_t)N_NODES * HD * 2);   // E_SL int2 (13.6MB)
    int2*   dec     = agg + E_SL;                           // E_SL int2 (13.6MB)
    float*  fsmall    = (float*)(dec + E_SL);
    float*  s_src     = fsmall;                             // N
    float*  s_dst     = s_src + N_NODES;                    // N
    float*  partials  = s_dst + N_NODES;                    // MEAN_BLOCKS*4*8
    float*  we_vec    = partials + MEAN_BLOCKS * 4 * 8;     // 16
    uint*   ltp       = (uint*)(we_vec + 16);               // 1
    float*  Wc        = (float*)(ltp + 1);                  // 32*64
    float*  bc        = Wc + F_INN * HD;                    // 64
    int*    row_ptr   = (int*)(bc + HD);                    // N+1
    int*    cursor    = row_ptr + N_NODES + 1;              // N
    int*    deg       = cursor + N_NODES;                   // N
    int*    blk_sums  = deg + N_NODES;                      // N_SCAN_BLOCKS
    int*    blk_off   = blk_sums + N_SCAN_BLOCKS;           // N_SCAN_BLOCKS

    const int NB_N256 = (N_NODES + 255) / 256;   // 391
    const int NB_EDGE = (E_SL + 255) / 256;      // 6641
    const int NB_AGG  = N_NODES / 4;             // 25000
    const int NB_DENSE = N_NODES / NPB;          // 3125

    // small precomputes + edge-ordered records
    k_init_small<<<1, 64, 0, stream>>>(edge_w, att_edge, we_vec);
    k_fuse_w<<<1, 256, 0, stream>>>(enc_w, enc_b, gat_w, Wc, bc);
    k_mean_edterm<<<MEAN_BLOCKS, 256, 0, stream>>>(eattr, src, we_vec, partials, rec_agg);
    k_mean_final<<<1, 256, 0, stream>>>(partials, we_vec, ltp);

    // CSR build: hist -> scan -> perm scatter (XCD-sharded) -> coalesced record build
    k_deg_init<<<NB_N256, 256, 0, stream>>>(deg);
    k_hist<<<N_EDGES / 256, 256, 0, stream>>>(dst, deg);
    k_scan1<<<N_SCAN_BLOCKS, SCAN_BLOCK, 0, stream>>>(deg, row_ptr, blk_sums);
    k_scan2<<<1, 256, 0, stream>>>(blk_sums, blk_off);
    k_scan3<<<NB_N256, 256, 0, stream>>>(row_ptr, blk_off, deg, cursor, perm);
    k_perm_scatter<<<PERM_BLOCKS, 256, 0, stream>>>(dst, cursor, perm);
    k_build<<<NB_EDGE, 256, 0, stream>>>(perm, rec_agg, ltp, agg, dec);

    // layer-0 projection (encoder folded into Wc/bc)
    k_xp0<<<NB_DENSE, 256, 0, stream>>>(x, Wc, bc, att_src, att_dst, xpb, s_src, s_dst);
    k_aggregate<0><<<NB_AGG, 256, 0, stream>>>(row_ptr, agg, s_src, s_dst,
                                               (const uint2*)xpb, gat_b, h);
    // GAT layer 1
    k_xp<<<NB_DENSE, 256, 0, stream>>>(h, gat_w + HD * HD, att_src + HD, att_dst + HD,
                                       xpb, s_src, s_dst);
    k_aggregate<1><<<NB_AGG, 256, 0, stream>>>(row_ptr, agg, s_src, s_dst,
                                               (const uint2*)xpb, gat_b + HD, h);

    // decoder: u1(bf16) -> xpb buffer, u2(fp32) -> h buffer
    k_umm<<<NB_DENSE, 256, 0, stream>>>(h, lp_w1, xpb, h);
    k_decode_csr<<<NB_AGG, 256, 0, stream>>>(row_ptr, dec, (const uint2*)xpb, h,
                                             lp_b1, lp_w2, lp_b2, out);
}

// Round 12
// 575.701 us; speedup vs baseline: 1.5767x; 1.0210x over previous
//
#include <hip/hip_runtime.h>
#include <hip/hip_bf16.h>
#include <math.h>

#define N_NODES 100000
#define N_EDGES 1600000
#define F_INN   32
#define F_EE    8
#define HD      64
#define E_SL    (N_EDGES + N_NODES)   // edges + self loops
#define NEG_SLOPE 0.2f
#define MEAN_BLOCKS 256
#define SCAN_BLOCK 512
#define N_SCAN_BLOCKS ((N_NODES + SCAN_BLOCK - 1) / SCAN_BLOCK)   // 196
#define SHARD_W (N_NODES / 8)         // 12500 nodes per XCD shard
#define PERM_BLOCKS 2048              // 256 blocks per shard
#define NPB 32                        // nodes per block in dense kernels (3125 blocks)

typedef int intv4 __attribute__((ext_vector_type(4)));   // native vec for nontemporal builtin

// ---------- helpers ----------
__device__ __forceinline__ float waveReduceSum(float v) {
#pragma unroll
    for (int off = 32; off > 0; off >>= 1) v += __shfl_down(v, off, 64);
    return v;
}
__device__ __forceinline__ float bf_lo(uint u) { return __uint_as_float(u << 16); }
__device__ __forceinline__ float bf_hi(uint u) { return __uint_as_float(u & 0xffff0000u); }
__device__ __forceinline__ uint pack_bf2(float a, float b) {
    __hip_bfloat16 ha = __float2bfloat16(a), hb = __float2bfloat16(b);
    unsigned short ua, ub;
    __builtin_memcpy(&ua, &ha, 2); __builtin_memcpy(&ub, &hb, 2);
    return (uint)ua | ((uint)ub << 16);
}

// ---------- K1: we_vec[l][k] = dot(edge_w[l][k,:], att_edge[l,:]) ----------
__global__ void k_init_small(const float* __restrict__ edge_w, const float* __restrict__ att_edge,
                             float* __restrict__ we_vec) {
    int t = threadIdx.x;
    if (t < 16) {
        int l = t >> 3, k = t & 7;
        const float* We = edge_w + l * F_EE * HD + k * HD;
        const float* ae = att_edge + l * HD;
        float s = 0.0f;
#pragma unroll
        for (int j = 0; j < HD; ++j) s += We[j] * ae[j];
        we_vec[l * 8 + k] = s;
    }
}

// ---------- K1b: fold encoder into layer-0 projection: Wc = enc_w@W0, bc = enc_b@W0 ----------
__global__ __launch_bounds__(256) void k_fuse_w(const float* __restrict__ enc_w,
                                                const float* __restrict__ enc_b,
                                                const float* __restrict__ W0,
                                                float* __restrict__ Wc, float* __restrict__ bc) {
    int t = threadIdx.x;
    for (int idx = t; idx < F_INN * HD; idx += 256) {
        int r = idx >> 6, c = idx & 63;
        float s = 0.0f;
#pragma unroll
        for (int k = 0; k < HD; ++k) s += enc_w[r * HD + k] * W0[k * HD + c];
        Wc[idx] = s;
    }
    if (t < HD) {
        float s = 0.0f;
#pragma unroll
        for (int k = 0; k < HD; ++k) s += enc_b[k] * W0[k * HD + t];
        bc[t] = s;
    }
}

// ---------- K2a: fused — mean partials, deg histogram, edge records {src, packed bf16 ed01} ----------
__global__ __launch_bounds__(256) void k_mean_edterm(const float* __restrict__ eattr,
                                                     const int* __restrict__ src,
                                                     const int* __restrict__ dst,
                                                     const float* __restrict__ we_vec,
                                                     float* __restrict__ partials,
                                                     int2* __restrict__ rec_agg,
                                                     int* __restrict__ deg) {
    __shared__ float sw[16];
    int t = threadIdx.x;
    if (t < 16) sw[t] = we_vec[t];
    __syncthreads();
    float p[8];
#pragma unroll
    for (int k = 0; k < 8; ++k) p[k] = 0.0f;
    for (int e = blockIdx.x * blockDim.x + t; e < N_EDGES; e += gridDim.x * blockDim.x) {
        const float4* row = (const float4*)(eattr + (size_t)e * F_EE);
        float4 r0 = row[0], r1 = row[1];
        p[0] += r0.x; p[1] += r0.y; p[2] += r0.z; p[3] += r0.w;
        p[4] += r1.x; p[5] += r1.y; p[6] += r1.z; p[7] += r1.w;
        float ed0 = r0.x * sw[0] + r0.y * sw[1] + r0.z * sw[2] + r0.w * sw[3]
                  + r1.x * sw[4] + r1.y * sw[5] + r1.z * sw[6] + r1.w * sw[7];
        float ed1 = r0.x * sw[8] + r0.y * sw[9] + r0.z * sw[10] + r0.w * sw[11]
                  + r1.x * sw[12] + r1.y * sw[13] + r1.z * sw[14] + r1.w * sw[15];
        rec_agg[e] = make_int2(src[e], (int)pack_bf2(ed0, ed1));
        atomicAdd(&deg[dst[e]], 1);   // fused histogram (deg pre-initialized to 1)
    }
#pragma unroll
    for (int k = 0; k < 8; ++k) p[k] = waveReduceSum(p[k]);
    int wave = t >> 6;
    if ((t & 63) == 0) {
        float* dstp = partials + ((size_t)blockIdx.x * 4 + wave) * 8;
#pragma unroll
        for (int k = 0; k < 8; ++k) dstp[k] = p[k];
    }
}

// ---------- K2b: finish mean; ltp = packed bf16 {loop_term0, loop_term1} ----------
__global__ __launch_bounds__(256) void k_mean_final(const float* __restrict__ partials,
                                                    const float* __restrict__ we_vec,
                                                    uint* __restrict__ ltp) {
    __shared__ float red[256];
    __shared__ float mean8[8];
    __shared__ float lt[2];
    int t = threadIdx.x;
    int k = t & 7;
    int chunk = t >> 3;
    float s = 0.0f;
    for (int i = chunk; i < MEAN_BLOCKS * 4; i += 32) s += partials[(size_t)i * 8 + k];
    red[t] = s;
    __syncthreads();
    if (t < 8) {
        float acc = 0.0f;
#pragma unroll
        for (int c = 0; c < 32; ++c) acc += red[c * 8 + t];
        mean8[t] = acc * (1.0f / N_EDGES);
    }
    __syncthreads();
    if (t < 2) {
        float acc = 0.0f;
#pragma unroll
        for (int kk = 0; kk < 8; ++kk) acc += mean8[kk] * we_vec[t * 8 + kk];
        lt[t] = acc;
    }
    __syncthreads();
    if (t == 0) ltp[0] = pack_bf2(lt[0], lt[1]);
}

// ---------- CSR build ----------
__global__ void k_deg_init(int* __restrict__ deg) {
    int i = blockIdx.x * 256 + threadIdx.x;
    if (i < N_NODES) deg[i] = 1;   // self-loop
}

__global__ __launch_bounds__(SCAN_BLOCK) void k_scan1(const int* __restrict__ deg,
                                                      int* __restrict__ row_ptr,
                                                      int* __restrict__ blk_sums) {
    __shared__ int sd[SCAN_BLOCK];
    int t = threadIdx.x;
    int i = blockIdx.x * SCAN_BLOCK + t;
    int v = (i < N_NODES) ? deg[i] : 0;
    sd[t] = v;
    for (int off = 1; off < SCAN_BLOCK; off <<= 1) {
        __syncthreads();
        int x = (t >= off) ? sd[t - off] : 0;
        __syncthreads();
        sd[t] += x;
    }
    __syncthreads();
    if (i < N_NODES) row_ptr[i] = sd[t] - v;
    if (t == SCAN_BLOCK - 1) blk_sums[blockIdx.x] = sd[t];
}

__global__ __launch_bounds__(256) void k_scan2(int* __restrict__ blk_sums,
                                               int* __restrict__ blk_off) {
    __shared__ int sd[256];
    int t = threadIdx.x;
    int v = (t < N_SCAN_BLOCKS) ? blk_sums[t] : 0;
    sd[t] = v;
    for (int off = 1; off < 256; off <<= 1) {
        __syncthreads();
        int x = (t >= off) ? sd[t - off] : 0;
        __syncthreads();
        sd[t] += x;
    }
    __syncthreads();
    if (t < N_SCAN_BLOCKS) blk_off[t] = sd[t] - v;
}

// finalize row_ptr, init cursor, and drop self-loop marker into the LAST slot of each segment
__global__ void k_scan3(int* __restrict__ row_ptr, const int* __restrict__ blk_off,
                        const int* __restrict__ deg,
                        int* __restrict__ cursor, int* __restrict__ perm) {
    int i = blockIdx.x * 256 + threadIdx.x;
    if (i < N_NODES) {
        int r = row_ptr[i] + blk_off[i / SCAN_BLOCK];
        row_ptr[i] = r;
        cursor[i] = r;
        perm[r + deg[i] - 1] = N_EDGES + i;   // self-loop marker
    }
    if (i == 0) row_ptr[N_NODES] = E_SL;
}

// kB: XCD-sharded perm scatter. dst is streamed with NONTEMPORAL loads so it
// doesn't evict the shard's dirty L2-resident perm slice (~0.85MB) — r11 showed
// 10x writeback amplification from exactly that thrash.
__global__ __launch_bounds__(256) void k_perm_scatter(const int* __restrict__ dst,
                                                      int* __restrict__ cursor,
                                                      int* __restrict__ perm) {
    int shard = blockIdx.x & 7;
    int lo = shard * SHARD_W, hi = lo + SHARD_W;
    const int nquad = N_EDGES / 4;
    int stride = (PERM_BLOCKS >> 3) * 256;
    for (int q = (blockIdx.x >> 3) * 256 + threadIdx.x; q < nquad; q += stride) {
        intv4 d4 = __builtin_nontemporal_load((const intv4*)dst + q);
#pragma unroll
        for (int k = 0; k < 4; ++k) {
            int d = d4[k];
            if (d >= lo && d < hi) {
                int pos = atomicAdd(&cursor[d], 1);
                perm[pos] = 4 * q + k;
            }
        }
    }
}

// kC: gather-build final CSR records (coalesced writes)
__global__ __launch_bounds__(256) void k_build(const int* __restrict__ perm,
                                               const int2* __restrict__ rec_agg,
                                               const uint* __restrict__ ltp,
                                               int2* __restrict__ agg,
                                               int2* __restrict__ dec) {
    int pos = blockIdx.x * 256 + threadIdx.x;
    if (pos >= E_SL) return;
    int p = perm[pos];
    if (p >= N_EDGES) {
        int n = p - N_EDGES;
        agg[pos] = make_int2(n, (int)ltp[0]);
        dec[pos] = make_int2(n, -1);
    } else {
        int2 ra = rec_agg[p];
        agg[pos] = ra;
        dec[pos] = make_int2(ra.x, p);
    }
}

// ---------- K3: layer-0 projection xp = x@Wc + bc — weight column in VGPRs, x broadcast via LDS ----------
__global__ __launch_bounds__(256) void k_xp0(const float* __restrict__ x,
                                             const float* __restrict__ Wc,
                                             const float* __restrict__ bc,
                                             const float* __restrict__ a_src,
                                             const float* __restrict__ a_dst,
                                             __hip_bfloat16* __restrict__ xpb,
                                             float* __restrict__ s_src,
                                             float* __restrict__ s_dst) {
    __shared__ float xr[NPB * F_INN];  // 4 KB
    int t = threadIdx.x;
    int j = t & 63, wv = t >> 6;
    float4 w[F_INN / 4];               // 8 VGPR float4s = weight column j
#pragma unroll
    for (int kk = 0; kk < F_INN / 4; ++kk) {
        w[kk].x = Wc[(4 * kk + 0) * HD + j];
        w[kk].y = Wc[(4 * kk + 1) * HD + j];
        w[kk].z = Wc[(4 * kk + 2) * HD + j];
        w[kk].w = Wc[(4 * kk + 3) * HD + j];
    }
    int n0 = blockIdx.x * NPB;
    ((float4*)xr)[t] = ((const float4*)(x + (size_t)n0 * F_INN))[t];  // 256*16B = 4KB exact
    __syncthreads();
    float asj = a_src[j], adj = a_dst[j], bcj = bc[j];
    for (int n = wv; n < NPB; n += 4) {
        const float4* hx = (const float4*)&xr[n * F_INN];
        float acc = bcj;
#pragma unroll
        for (int kk = 0; kk < F_INN / 4; ++kk) {
            float4 hv = hx[kk];   // wave-uniform broadcast ds_read_b128
            acc += hv.x * w[kk].x + hv.y * w[kk].y + hv.z * w[kk].z + hv.w * w[kk].w;
        }
        int node = n0 + n;
        xpb[(size_t)node * HD + j] = __float2bfloat16(acc);
        float ts = waveReduceSum(acc * asj);
        float td = waveReduceSum(acc * adj);
        if (j == 0) { s_src[node] = ts; s_dst[node] = td; }
    }
}

// ---------- K4: xp(bf16) = h @ W (layer 1) — weight column in VGPRs ----------
__global__ __launch_bounds__(256) void k_xp(const float* __restrict__ h, const float* __restrict__ W,
                                            const float* __restrict__ a_src, const float* __restrict__ a_dst,
                                            __hip_bfloat16* __restrict__ xpb, float* __restrict__ s_src,
                                            float* __restrict__ s_dst) {
    __shared__ float hr[NPB * HD];     // 8 KB
    int t = threadIdx.x;
    int j = t & 63, wv = t >> 6;
    float4 w[HD / 4];                  // 16 float4s = 64 VGPRs
#pragma unroll
    for (int kk = 0; kk < HD / 4; ++kk) {
        w[kk].x = W[(4 * kk + 0) * HD + j];
        w[kk].y = W[(4 * kk + 1) * HD + j];
        w[kk].z = W[(4 * kk + 2) * HD + j];
        w[kk].w = W[(4 * kk + 3) * HD + j];
    }
    int n0 = blockIdx.x * NPB;
#pragma unroll
    for (int i = 0; i < 2; ++i)
        ((float4*)hr)[t + i * 256] = ((const float4*)(h + (size_t)n0 * HD))[t + i * 256];
    __syncthreads();
    float asj = a_src[j], adj = a_dst[j];
    for (int n = wv; n < NPB; n += 4) {
        const float4* hx = (const float4*)&hr[n * HD];
        float acc = 0.0f;
#pragma unroll
        for (int kk = 0; kk < HD / 4; ++kk) {
            float4 hv = hx[kk];   // broadcast ds_read_b128
            acc += hv.x * w[kk].x + hv.y * w[kk].y + hv.z * w[kk].z + hv.w * w[kk].w;
        }
        int node = n0 + n;
        xpb[(size_t)node * HD + j] = __float2bfloat16(acc);
        float ts = waveReduceSum(acc * asj);
        float td = waveReduceSum(acc * adj);
        if (j == 0) { s_src[node] = ts; s_dst[node] = td; }
    }
}

// ---------- K5: gather-aggregate — wave/node, 16-lane groups, 8 edges/iter in flight ----------
template <int LAYER>
__global__ __launch_bounds__(256) void k_aggregate(const int* __restrict__ row_ptr,
                                                   const int2* __restrict__ agg,
                                                   const float* __restrict__ s_src,
                                                   const float* __restrict__ s_dst,
                                                   const uint2* __restrict__ xpr,   // bf16 x4 per lane
                                                   const float* __restrict__ bias,
                                                   float* __restrict__ h) {
    int t = threadIdx.x;
    int node = blockIdx.x * 4 + (t >> 6);    // grid exact: N/4
    int lane = t & 63;
    int g = lane >> 4, li = lane & 15;
    int start = row_ptr[node], end = row_ptr[node + 1];
    float sd = s_dst[node];
    float ax = 0.0f, ay = 0.0f, az = 0.0f, aw = 0.0f, den = 0.0f;
    int i = start;
    for (; i + 8 <= end; i += 8) {
        int2 r0 = agg[i + g];
        int2 r1 = agg[i + 4 + g];
        int sp0 = r0.x, sp1 = r1.x;
        uint2 u0 = xpr[(size_t)sp0 * 16 + li];
        uint2 u1 = xpr[(size_t)sp1 * 16 + li];
        float a0 = s_src[sp0] + sd + (LAYER == 0 ? bf_lo((uint)r0.y) : bf_hi((uint)r0.y));
        float a1 = s_src[sp1] + sd + (LAYER == 0 ? bf_lo((uint)r1.y) : bf_hi((uint)r1.y));
        a0 = a0 > 0.0f ? a0 : NEG_SLOPE * a0;
        a1 = a1 > 0.0f ? a1 : NEG_SLOPE * a1;
        float ex0 = __expf(a0), ex1 = __expf(a1);
        den += ex0 + ex1;
        ax += ex0 * bf_lo(u0.x) + ex1 * bf_lo(u1.x);
        ay += ex0 * bf_hi(u0.x) + ex1 * bf_hi(u1.x);
        az += ex0 * bf_lo(u0.y) + ex1 * bf_lo(u1.y);
        aw += ex0 * bf_hi(u0.y) + ex1 * bf_hi(u1.y);
    }
    for (; i < end; i += 4) {
        int idx = i + g;
        bool valid = idx < end;
        int2 r = agg[valid ? idx : end - 1];
        int sp = r.x;
        uint2 u = xpr[(size_t)sp * 16 + li];
        float a = s_src[sp] + sd + (LAYER == 0 ? bf_lo((uint)r.y) : bf_hi((uint)r.y));
        a = a > 0.0f ? a : NEG_SLOPE * a;
        float ex = valid ? __expf(a) : 0.0f;
        den += ex;
        ax += ex * bf_lo(u.x);
        ay += ex * bf_hi(u.x);
        az += ex * bf_lo(u.y);
        aw += ex * bf_hi(u.y);
    }
    den += __shfl_down(den, 32, 64); ax += __shfl_down(ax, 32, 64);
    ay  += __shfl_down(ay, 32, 64); az += __shfl_down(az, 32, 64);
    aw  += __shfl_down(aw, 32, 64);
    den += __shfl_down(den, 16, 64); ax += __shfl_down(ax, 16, 64);
    ay  += __shfl_down(ay, 16, 64); az += __shfl_down(az, 16, 64);
    aw  += __shfl_down(aw, 16, 64);
    if (lane < 16) {
        float inv = 1.0f / (den + 1e-16f);
        float4 b4 = ((const float4*)bias)[li];
        float4 v;
        v.x = fmaxf(ax * inv + b4.x, 0.0f);
        v.y = fmaxf(ay * inv + b4.y, 0.0f);
        v.z = fmaxf(az * inv + b4.z, 0.0f);
        v.w = fmaxf(aw * inv + b4.w, 0.0f);
        ((float4*)(h + (size_t)node * HD))[li] = v;
    }
}

// ---------- K6: u1(bf16)=h@W1a, u2(f32)=h@W1b — both weight columns in VGPRs ----------
// (u2 aliases h: tile staged to LDS before any write)
__global__ __launch_bounds__(256) void k_umm(const float* __restrict__ h, const float* __restrict__ w1,
                                             __hip_bfloat16* __restrict__ u1b, float* __restrict__ u2) {
    __shared__ float hr[NPB * HD];     // 8 KB
    int t = threadIdx.x;
    int j = t & 63, wv = t >> 6;
    float4 wa[HD / 4], wb[HD / 4];     // 128 VGPRs
#pragma unroll
    for (int kk = 0; kk < HD / 4; ++kk) {
        wa[kk].x = w1[(4 * kk + 0) * HD + j];
        wa[kk].y = w1[(4 * kk + 1) * HD + j];
        wa[kk].z = w1[(4 * kk + 2) * HD + j];
        wa[kk].w = w1[(4 * kk + 3) * HD + j];
        wb[kk].x = w1[(HD + 4 * kk + 0) * HD + j];
        wb[kk].y = w1[(HD + 4 * kk + 1) * HD + j];
        wb[kk].z = w1[(HD + 4 * kk + 2) * HD + j];
        wb[kk].w = w1[(HD + 4 * kk + 3) * HD + j];
    }
    int n0 = blockIdx.x * NPB;
#pragma unroll
    for (int i = 0; i < 2; ++i)
        ((float4*)hr)[t + i * 256] = ((const float4*)(h + (size_t)n0 * HD))[t + i * 256];
    __syncthreads();
    for (int n = wv; n < NPB; n += 4) {
        const float4* hx = (const float4*)&hr[n * HD];
        float a1 = 0.0f, a2 = 0.0f;
#pragma unroll
        for (int kk = 0; kk < HD / 4; ++kk) {
            float4 hv = hx[kk];   // broadcast ds_read_b128
            a1 += hv.x * wa[kk].x + hv.y * wa[kk].y + hv.z * wa[kk].z + hv.w * wa[kk].w;
            a2 += hv.x * wb[kk].x + hv.y * wb[kk].y + hv.z * wb[kk].z + hv.w * wb[kk].w;
        }
        int node = n0 + n;
        u1b[(size_t)node * HD + j] = __float2bfloat16(a1);
        u2[(size_t)node * HD + j] = a2;
    }
}

// ---------- K7: CSR decode — wave/node, 16-lane groups, 8 edges/iter, width-16 reduce ----------
__global__ __launch_bounds__(256) void k_decode_csr(const int* __restrict__ row_ptr,
                                                    const int2* __restrict__ dec,
                                                    const uint2* __restrict__ u1r,  // bf16 x4 per lane
                                                    const float* __restrict__ u2,
                                                    const float* __restrict__ b1,
                                                    const float* __restrict__ w2,
                                                    const float* __restrict__ b2,
                                                    float* __restrict__ out) {
    int t = threadIdx.x;
    int node = blockIdx.x * 4 + (t >> 6);    // grid exact: N/4
    int lane = t & 63;
    int g = lane >> 4, li = lane & 15;
    float4 c4 = ((const float4*)(u2 + (size_t)node * HD))[li];
    float4 b14 = ((const float4*)b1)[li];
    float4 w4 = ((const float4*)w2)[li];
    c4.x += b14.x; c4.y += b14.y; c4.z += b14.z; c4.w += b14.w;
    float bb = b2[0];
    int start = row_ptr[node], end = row_ptr[node + 1];
    int i = start;
    for (; i + 8 <= end; i += 8) {
        int2 e0 = dec[i + g];
        int2 e1 = dec[i + 4 + g];
        uint2 ua = u1r[(size_t)e0.x * 16 + li];
        uint2 ub = u1r[(size_t)e1.x * 16 + li];
        float p0 = fmaxf(bf_lo(ua.x) + c4.x, 0.0f) * w4.x
                 + fmaxf(bf_hi(ua.x) + c4.y, 0.0f) * w4.y
                 + fmaxf(bf_lo(ua.y) + c4.z, 0.0f) * w4.z
                 + fmaxf(bf_hi(ua.y) + c4.w, 0.0f) * w4.w;
        float p1 = fmaxf(bf_lo(ub.x) + c4.x, 0.0f) * w4.x
                 + fmaxf(bf_hi(ub.x) + c4.y, 0.0f) * w4.y
                 + fmaxf(bf_lo(ub.y) + c4.z, 0.0f) * w4.z
                 + fmaxf(bf_hi(ub.y) + c4.w, 0.0f) * w4.w;
#pragma unroll
        for (int off = 8; off > 0; off >>= 1) {
            p0 += __shfl_down(p0, off, 16);
            p1 += __shfl_down(p1, off, 16);
        }
        if (li == 0) {
            if (e0.y >= 0) out[e0.y] = 1.0f / (1.0f + __expf(-(p0 + bb)));
            if (e1.y >= 0) out[e1.y] = 1.0f / (1.0f + __expf(-(p1 + bb)));
        }
    }
    for (; i < end; i += 4) {
        int idx = i + g;
        bool valid = idx < end;
        int2 e = dec[valid ? idx : end - 1];
        uint2 u = u1r[(size_t)e.x * 16 + li];
        float p = fmaxf(bf_lo(u.x) + c4.x, 0.0f) * w4.x
                + fmaxf(bf_hi(u.x) + c4.y, 0.0f) * w4.y
                + fmaxf(bf_lo(u.y) + c4.z, 0.0f) * w4.z
                + fmaxf(bf_hi(u.y) + c4.w, 0.0f) * w4.w;
#pragma unroll
        for (int off = 8; off > 0; off >>= 1) p += __shfl_down(p, off, 16);
        if (li == 0 && valid && e.y >= 0)
            out[e.y] = 1.0f / (1.0f + __expf(-(p + bb)));
    }
}

extern "C" void kernel_launch(void* const* d_in, const int* in_sizes, int n_in,
                              void* d_out, int out_size, void* d_ws, size_t ws_size,
                              hipStream_t stream) {
    const float* x        = (const float*)d_in[0];
    const int*   eidx     = (const int*)d_in[1];
    const float* eattr    = (const float*)d_in[2];
    const float* enc_w    = (const float*)d_in[3];
    const float* enc_b    = (const float*)d_in[4];
    const float* gat_w    = (const float*)d_in[5];
    const float* att_src  = (const float*)d_in[6];
    const float* att_dst  = (const float*)d_in[7];
    const float* edge_w   = (const float*)d_in[8];
    const float* att_edge = (const float*)d_in[9];
    const float* gat_b    = (const float*)d_in[10];
    const float* lp_w1    = (const float*)d_in[11];
    const float* lp_b1    = (const float*)d_in[12];
    const float* lp_w2    = (const float*)d_in[13];
    const float* lp_b2    = (const float*)d_in[14];
    float* out = (float*)d_out;

    const int* src = eidx;
    const int* dst = eidx + N_EDGES;

    // ---- workspace layout ----
    float* ws = (float*)d_ws;
    float*  h       = ws;                                   // N*64 f32 (u2 after k_umm)
    int2*   rec_agg = (int2*)h;                             // E int2 (alias; dead before aggregate<0>)
    int*    perm    = (int*)(rec_agg + N_EDGES);            // E_SL int (alias)
    __hip_bfloat16* xpb = (__hip_bfloat16*)(h + (size_t)N_NODES * HD);  // N*64 bf16 (u1b after k_umm)
    int2*   agg     = (int2*)((char*)xpb + (size_t)N_NODES * HD * 2);   // E_SL int2 (13.6MB)
    int2*   dec     = agg + E_SL;                           // E_SL int2 (13.6MB)
    float*  fsmall    = (float*)(dec + E_SL);
    float*  s_src     = fsmall;                             // N
    float*  s_dst     = s_src + N_NODES;                    // N
    float*  partials  = s_dst + N_NODES;                    // MEAN_BLOCKS*4*8
    float*  we_vec    = partials + MEAN_BLOCKS * 4 * 8;     // 16
    uint*   ltp       = (uint*)(we_vec + 16);               // 1
    float*  Wc        = (float*)(ltp + 1);                  // 32*64
    float*  bc        = Wc + F_INN * HD;                    // 64
    int*    row_ptr   = (int*)(bc + HD);                    // N+1
    int*    cursor    = row_ptr + N_NODES + 1;              // N
    int*    deg       = cursor + N_NODES;                   // N
    int*    blk_sums  = deg + N_NODES;                      // N_SCAN_BLOCKS
    int*    blk_off   = blk_sums + N_SCAN_BLOCKS;           // N_SCAN_BLOCKS

    const int NB_N256 = (N_NODES + 255) / 256;   // 391
    const int NB_EDGE = (E_SL + 255) / 256;      // 6641
    const int NB_AGG  = N_NODES / 4;             // 25000
    const int NB_DENSE = N_NODES / NPB;          // 3125

    // small precomputes + edge-ordered records (+fused deg histogram)
    k_init_small<<<1, 64, 0, stream>>>(edge_w, att_edge, we_vec);
    k_fuse_w<<<1, 256, 0, stream>>>(enc_w, enc_b, gat_w, Wc, bc);
    k_deg_init<<<NB_N256, 256, 0, stream>>>(deg);
    k_mean_edterm<<<MEAN_BLOCKS, 256, 0, stream>>>(eattr, src, dst, we_vec,
                                                   partials, rec_agg, deg);
    k_mean_final<<<1, 256, 0, stream>>>(partials, we_vec, ltp);

    // CSR build: scan -> perm scatter (XCD-sharded, NT dst loads) -> coalesced record build
    k_scan1<<<N_SCAN_BLOCKS, SCAN_BLOCK, 0, stream>>>(deg, row_ptr, blk_sums);
    k_scan2<<<1, 256, 0, stream>>>(blk_sums, blk_off);
    k_scan3<<<NB_N256, 256, 0, stream>>>(row_ptr, blk_off, deg, cursor, perm);
    k_perm_scatter<<<PERM_BLOCKS, 256, 0, stream>>>(dst, cursor, perm);
    k_build<<<NB_EDGE, 256, 0, stream>>>(perm, rec_agg, ltp, agg, dec);

    // layer-0 projection (encoder folded into Wc/bc)
    k_xp0<<<NB_DENSE, 256, 0, stream>>>(x, Wc, bc, att_src, att_dst, xpb, s_src, s_dst);
    k_aggregate<0><<<NB_AGG, 256, 0, stream>>>(row_ptr, agg, s_src, s_dst,
                                               (const uint2*)xpb, gat_b, h);
    // GAT layer 1
    k_xp<<<NB_DENSE, 256, 0, stream>>>(h, gat_w + HD * HD, att_src + HD, att_dst + HD,
                                       xpb, s_src, s_dst);
    k_aggregate<1><<<NB_AGG, 256, 0, stream>>>(row_ptr, agg, s_src, s_dst,
                                               (const uint2*)xpb, gat_b + HD, h);

    // decoder: u1(bf16) -> xpb buffer, u2(fp32) -> h buffer
    k_umm<<<NB_DENSE, 256, 0, stream>>>(h, lp_w1, xpb, h);
    k_decode_csr<<<NB_AGG, 256, 0, stream>>>(row_ptr, dec, (const uint2*)xpb, h,
                                             lp_b1, lp_w2, lp_b2, out);
}